// Round 3
// baseline (3199.523 us; speedup 1.0000x reference)
//
#include <hip/hip_runtime.h>
#include <math.h>

// OlmoeSparseMoeBlock: T=8192, H=2048, E=64, I=1024, top-8.
// fp64 router -> top8 -> padded expert segments (PM=128)
// v3: NO weight convert pass. GEMMs read fp32 weights directly, converting
//     in-kernel via v_cvt_pk_bf16_f32 into XOR-swizzled LDS. Activations
//     (xb, hbuf) stay bf16 + global_load_lds(16B) pre-swizzled-source.
// Tier A: down writes per-slot y (bf16), gather combines (no atomics).
// Tier B (small ws): atomic down epilogue.

#define NEXP 64
#define HID 2048
#define INTER 1024
#define TOPK 8
#define PM 128
#define MAX_TILES 576
#define CAP (MAX_TILES * PM)
#define BK 64

typedef __attribute__((ext_vector_type(8))) short bf16x8;
typedef __attribute__((ext_vector_type(4))) float f32x4;

__device__ __forceinline__ unsigned short f2bf(float f) {
  unsigned int u = __float_as_uint(f);
  u += 0x7fffu + ((u >> 16) & 1u);   // RNE
  return (unsigned short)(u >> 16);
}
__device__ __forceinline__ float bf2f(unsigned short u) {
  return __uint_as_float(((unsigned int)u) << 16);
}

// element-index XOR swizzle for [row][BK] bf16 tiles (16B-granular)
__device__ __forceinline__ int SW(int row, int k) {
  return (row * BK + k) ^ ((row & 7) << 3);
}

__device__ __forceinline__ void gload16(const unsigned short* g, unsigned short* l) {
  __builtin_amdgcn_global_load_lds((const __attribute__((address_space(1))) unsigned int*)g,
                                   (__attribute__((address_space(3))) unsigned int*)l, 16, 0, 0);
}

// stage 4 granules (32 fp32 elems) of row r into swizzled bf16 LDS tile
__device__ __forceinline__ void stageB_f32(const float* __restrict__ rowsrc /* row base */,
                                           int r, int gbase, unsigned short* lds) {
#pragma unroll
  for (int j = 0; j < 4; j++) {
    int g = gbase + j;
    const float4* p = (const float4*)(rowsrc + g * 8);
    float4 v0 = p[0], v1 = p[1];
    unsigned int w0, w1, w2, w3;
    asm("v_cvt_pk_bf16_f32 %0, %1, %2" : "=v"(w0) : "v"(v0.x), "v"(v0.y));
    asm("v_cvt_pk_bf16_f32 %0, %1, %2" : "=v"(w1) : "v"(v0.z), "v"(v0.w));
    asm("v_cvt_pk_bf16_f32 %0, %1, %2" : "=v"(w2) : "v"(v1.x), "v"(v1.y));
    asm("v_cvt_pk_bf16_f32 %0, %1, %2" : "=v"(w3) : "v"(v1.z), "v"(v1.w));
    uint4 w = {w0, w1, w2, w3};
    *(uint4*)&lds[SW(r, g * 8)] = w;
  }
}

// ---------------- init ----------------
__global__ void init_kernel(float* out, int* slot_token, int* counts, int total, int zero_out) {
  int stride = gridDim.x * blockDim.x;
  for (int i = blockIdx.x * blockDim.x + threadIdx.x; i < total; i += stride) {
    if (zero_out) out[i] = 0.f;
    if (i < CAP) slot_token[i] = -1;
    if (i < NEXP) counts[i] = 0;
  }
}

// ---------------- x fp32 -> bf16 ----------------
__global__ void cvt_kernel(const float* __restrict__ src, unsigned short* __restrict__ dst, int n4) {
  int stride = gridDim.x * blockDim.x;
  for (int i = blockIdx.x * blockDim.x + threadIdx.x; i < n4; i += stride) {
    float4 v = ((const float4*)src)[i];
    ushort4 b;
    b.x = f2bf(v.x); b.y = f2bf(v.y); b.z = f2bf(v.z); b.w = f2bf(v.w);
    ((ushort4*)dst)[i] = b;
  }
}

// ---------------- router: fp64 logits [T][64] ----------------
__global__ void router_kernel(const float* __restrict__ x, const float* __restrict__ rw,
                              double* __restrict__ logits) {
  int t0 = blockIdx.x * 64;
  __shared__ float xs[64][33];
  __shared__ float wsm[64][33];
  int tid = threadIdx.x;
  int ti = tid >> 4, ei = tid & 15;
  double acc[4][4];
  for (int i = 0; i < 4; i++)
    for (int j = 0; j < 4; j++) acc[i][j] = 0.0;
  int srow = tid >> 3, sc = (tid & 7) * 4;
  for (int kb = 0; kb < HID; kb += 32) {
    for (int p = 0; p < 2; p++) {
      int r2 = srow + p * 32;
      float4 xv = *(const float4*)&x[(size_t)(t0 + r2) * HID + kb + sc];
      xs[r2][sc] = xv.x; xs[r2][sc + 1] = xv.y; xs[r2][sc + 2] = xv.z; xs[r2][sc + 3] = xv.w;
      float4 wv = *(const float4*)&rw[(size_t)r2 * HID + kb + sc];
      wsm[r2][sc] = wv.x; wsm[r2][sc + 1] = wv.y; wsm[r2][sc + 2] = wv.z; wsm[r2][sc + 3] = wv.w;
    }
    __syncthreads();
    for (int kk = 0; kk < 32; kk++) {
      float xa[4], wb[4];
      for (int i = 0; i < 4; i++) xa[i] = xs[ti * 4 + i][kk];
      for (int j = 0; j < 4; j++) wb[j] = wsm[ei * 4 + j][kk];
      for (int i = 0; i < 4; i++)
        for (int j = 0; j < 4; j++) acc[i][j] += (double)xa[i] * (double)wb[j];
    }
    __syncthreads();
  }
  for (int i = 0; i < 4; i++)
    for (int j = 0; j < 4; j++)
      logits[(size_t)(t0 + ti * 4 + i) * NEXP + ei * 4 + j] = acc[i][j];
}

// ---------------- softmax + top8 + counts ----------------
__global__ void topk_kernel(const double* __restrict__ logits, float* __restrict__ topk_w,
                            int* __restrict__ topk_i, int* __restrict__ counts, int T) {
  int t = blockIdx.x * 4 + (threadIdx.x >> 6);
  int lane = threadIdx.x & 63;
  if (t >= T) return;
  double v = logits[(size_t)t * NEXP + lane];
  double m = v;
  for (int off = 32; off; off >>= 1) {
    double o = __shfl_xor(m, off);
    if (o > m) m = o;
  }
  double ex = exp(v - m);
  double s = ex;
  for (int off = 32; off; off >>= 1) s += __shfl_xor(s, off);
  double cur = ex / s;
  for (int k = 0; k < TOPK; k++) {
    double bv = cur; int bi = lane;
    for (int off = 32; off; off >>= 1) {
      double ov = __shfl_xor(bv, off);
      int oi = __shfl_xor(bi, off);
      if (ov > bv || (ov == bv && oi < bi)) { bv = ov; bi = oi; }
    }
    if (lane == k) {
      topk_w[t * TOPK + k] = (float)bv;
      topk_i[t * TOPK + k] = bi;
      atomicAdd(&counts[bi], 1);
    }
    if (lane == bi) cur = -1.0;
  }
}

// ---------------- scan ----------------
__global__ void scan_kernel(const int* __restrict__ counts, int* cursor,
                            int* tile_expert, int* n_tiles_p) {
  if (threadIdx.x == 0 && blockIdx.x == 0) {
    int nt = 0;
    for (int e = 0; e < NEXP; e++) {
      cursor[e] = nt * PM;
      int c = counts[e];
      int k = (c + PM - 1) / PM;
      for (int i = 0; i < k; i++) tile_expert[nt++] = e;
    }
    *n_tiles_p = nt;
  }
}

// ---------------- scatter ----------------
__global__ void scatter_kernel(const int* __restrict__ topk_i, const float* __restrict__ topk_w,
                               int* cursor, int* slot_token, float* slot_w,
                               int* slot_of, int T) {
  int t = blockIdx.x * blockDim.x + threadIdx.x;
  if (t >= T) return;
  for (int k = 0; k < TOPK; k++) {
    int e = topk_i[t * TOPK + k];
    int pos = atomicAdd(&cursor[e], 1);
    slot_token[pos] = t;
    slot_w[pos] = topk_w[t * TOPK + k];
    slot_of[t * TOPK + k] = pos;
  }
}

// =====================================================================
// gate_up GEMM: A = xb (bf16, gload_lds), B = gup fp32 (reg->cvt_pk->LDS)
// =====================================================================
__global__ __launch_bounds__(256, 2) void gateup_v3(
    const unsigned short* __restrict__ xb, const float* __restrict__ gup,
    const int* __restrict__ slot_token, const int* __restrict__ tile_expert,
    const int* __restrict__ n_tiles_p, unsigned short* __restrict__ hbuf) {
  int tile = blockIdx.y;
  if (tile >= *n_tiles_p) return;
  int e = tile_expert[tile];
  int slot0 = tile * PM;
  int n0 = blockIdx.x * 128;
  __shared__ __align__(16) unsigned short As[128 * BK];
  __shared__ __align__(16) unsigned short Bgs[128 * BK];
  __shared__ __align__(16) unsigned short Bus[128 * BK];
  int tid = threadIdx.x;
  int wid = tid >> 6, lane = tid & 63;
  int lrow = lane >> 3, pc = lane & 7;

  // A staging: per-lane pre-swizzled global src, linear LDS dest
  const unsigned short* aptr[4];
  unsigned short* lA[4];
#pragma unroll
  for (int i = 0; i < 4; i++) {
    int r = wid * 32 + i * 8 + lrow;
    int sc = pc ^ (r & 7);
    int tok = slot_token[slot0 + r]; if (tok < 0) tok = 0;
    aptr[i] = xb + (size_t)tok * HID + sc * 8;
    lA[i] = &As[(wid * 32 + i * 8) * BK];
  }
  // B staging: thread -> (row, 4 granules)
  int br = tid >> 1, bg = (tid & 1) * 4;
  const float* grow = gup + ((size_t)e * (2 * INTER) + (n0 + br)) * HID;
  const float* urow = grow + (size_t)INTER * HID;

  f32x4 zero = {0.f, 0.f, 0.f, 0.f};
  f32x4 accg[4][4], accu[4][4];
#pragma unroll
  for (int i = 0; i < 4; i++)
#pragma unroll
    for (int j = 0; j < 4; j++) { accg[i][j] = zero; accu[i][j] = zero; }

  int wm = wid >> 1, wn = wid & 1, lr = lane & 15, lk = lane >> 4;

  for (int kb = 0; kb < HID; kb += BK) {
#pragma unroll
    for (int i = 0; i < 4; i++) gload16(aptr[i] + kb, lA[i]);
    stageB_f32(grow + kb, br, bg, Bgs);
    stageB_f32(urow + kb, br, bg, Bus);
    __syncthreads();
#pragma unroll
    for (int kk = 0; kk < BK; kk += 32) {
      bf16x8 a[4], bgf[4], buf[4];
#pragma unroll
      for (int mf = 0; mf < 4; mf++)
        a[mf] = *(const bf16x8*)&As[SW(wm * 64 + mf * 16 + lr, kk + lk * 8)];
#pragma unroll
      for (int nf = 0; nf < 4; nf++) {
        bgf[nf] = *(const bf16x8*)&Bgs[SW(wn * 64 + nf * 16 + lr, kk + lk * 8)];
        buf[nf] = *(const bf16x8*)&Bus[SW(wn * 64 + nf * 16 + lr, kk + lk * 8)];
      }
#pragma unroll
      for (int mf = 0; mf < 4; mf++)
#pragma unroll
        for (int nf = 0; nf < 4; nf++) {
          accg[mf][nf] = __builtin_amdgcn_mfma_f32_16x16x32_bf16(a[mf], bgf[nf], accg[mf][nf], 0, 0, 0);
          accu[mf][nf] = __builtin_amdgcn_mfma_f32_16x16x32_bf16(a[mf], buf[nf], accu[mf][nf], 0, 0, 0);
        }
    }
    __syncthreads();
  }
#pragma unroll
  for (int mf = 0; mf < 4; mf++)
#pragma unroll
    for (int nf = 0; nf < 4; nf++)
#pragma unroll
      for (int r = 0; r < 4; r++) {
        int row = wm * 64 + mf * 16 + lk * 4 + r;
        int col = n0 + wn * 64 + nf * 16 + lr;
        float g = accg[mf][nf][r];
        float u = accu[mf][nf][r];
        float hv = (g / (1.f + __expf(-g))) * u;
        hbuf[(size_t)(slot0 + row) * INTER + col] = f2bf(hv);
      }
}

// =====================================================================
// down GEMM: A = hbuf (bf16, gload_lds), B = dwn fp32 (reg->cvt_pk->LDS)
// =====================================================================
template <bool STORE_Y>
__global__ __launch_bounds__(256, 3) void down_v3(
    const unsigned short* __restrict__ hbuf, const float* __restrict__ dwn,
    const int* __restrict__ slot_token, const float* __restrict__ slot_w,
    const int* __restrict__ tile_expert, const int* __restrict__ n_tiles_p,
    unsigned short* __restrict__ ybuf, float* __restrict__ out) {
  int tile = blockIdx.y;
  if (tile >= *n_tiles_p) return;
  int e = tile_expert[tile];
  int slot0 = tile * PM;
  int n0 = blockIdx.x * 128;
  __shared__ __align__(16) unsigned short Hs[128 * BK];
  __shared__ __align__(16) unsigned short Bd[128 * BK];
  int tid = threadIdx.x;
  int wid = tid >> 6, lane = tid & 63;
  int lrow = lane >> 3, pc = lane & 7;

  const unsigned short* hptr[4];
  unsigned short* lH[4];
#pragma unroll
  for (int i = 0; i < 4; i++) {
    int r = wid * 32 + i * 8 + lrow;
    int sc = pc ^ (r & 7);
    hptr[i] = hbuf + (size_t)(slot0 + r) * INTER + sc * 8;
    lH[i] = &Hs[(wid * 32 + i * 8) * BK];
  }
  int br = tid >> 1, bg = (tid & 1) * 4;
  const float* drow = dwn + ((size_t)e * HID + (n0 + br)) * INTER;

  f32x4 zero = {0.f, 0.f, 0.f, 0.f};
  f32x4 acc[4][4];
#pragma unroll
  for (int i = 0; i < 4; i++)
#pragma unroll
    for (int j = 0; j < 4; j++) acc[i][j] = zero;

  int wm = wid >> 1, wn = wid & 1, lr = lane & 15, lk = lane >> 4;

  for (int kb = 0; kb < INTER; kb += BK) {
#pragma unroll
    for (int i = 0; i < 4; i++) gload16(hptr[i] + kb, lH[i]);
    stageB_f32(drow + kb, br, bg, Bd);
    __syncthreads();
#pragma unroll
    for (int kk = 0; kk < BK; kk += 32) {
      bf16x8 a[4], b[4];
#pragma unroll
      for (int mf = 0; mf < 4; mf++)
        a[mf] = *(const bf16x8*)&Hs[SW(wm * 64 + mf * 16 + lr, kk + lk * 8)];
#pragma unroll
      for (int nf = 0; nf < 4; nf++)
        b[nf] = *(const bf16x8*)&Bd[SW(wn * 64 + nf * 16 + lr, kk + lk * 8)];
#pragma unroll
      for (int mf = 0; mf < 4; mf++)
#pragma unroll
        for (int nf = 0; nf < 4; nf++)
          acc[mf][nf] = __builtin_amdgcn_mfma_f32_16x16x32_bf16(a[mf], b[nf], acc[mf][nf], 0, 0, 0);
    }
    __syncthreads();
  }
#pragma unroll
  for (int mf = 0; mf < 4; mf++)
#pragma unroll
    for (int r = 0; r < 4; r++) {
      int row = wm * 64 + mf * 16 + lk * 4 + r;
      int slot = slot0 + row;
      if (STORE_Y) {
#pragma unroll
        for (int nf = 0; nf < 4; nf++) {
          int col = n0 + wn * 64 + nf * 16 + lr;
          ybuf[(size_t)slot * HID + col] = f2bf(acc[mf][nf][r]);
        }
      } else {
        int t = slot_token[slot];
        if (t < 0) continue;
        float w = slot_w[slot];
#pragma unroll
        for (int nf = 0; nf < 4; nf++) {
          int col = n0 + wn * 64 + nf * 16 + lr;
          atomicAdd(&out[(size_t)t * HID + col], w * acc[mf][nf][r]);
        }
      }
    }
}

// ---------------- gather: out[t] = sum_k w_k * y[slot(t,k)] ----------------
__global__ void gather_kernel(const unsigned short* __restrict__ ybuf,
                              const int* __restrict__ slot_of,
                              const float* __restrict__ topk_w,
                              float* __restrict__ out) {
  int t = blockIdx.x;
  int c0 = threadIdx.x * 8;
  int slots[TOPK]; float w[TOPK];
#pragma unroll
  for (int k = 0; k < TOPK; k++) {
    slots[k] = slot_of[t * TOPK + k];
    w[k] = topk_w[t * TOPK + k];
  }
  float acc[8];
#pragma unroll
  for (int j = 0; j < 8; j++) acc[j] = 0.f;
#pragma unroll
  for (int k = 0; k < TOPK; k++) {
    const ushort4* p = (const ushort4*)(ybuf + (size_t)slots[k] * HID + c0);
    ushort4 v0 = p[0], v1 = p[1];
    acc[0] += w[k] * bf2f(v0.x); acc[1] += w[k] * bf2f(v0.y);
    acc[2] += w[k] * bf2f(v0.z); acc[3] += w[k] * bf2f(v0.w);
    acc[4] += w[k] * bf2f(v1.x); acc[5] += w[k] * bf2f(v1.y);
    acc[6] += w[k] * bf2f(v1.z); acc[7] += w[k] * bf2f(v1.w);
  }
  float4* o = (float4*)(out + (size_t)t * HID + c0);
  float4 o0 = {acc[0], acc[1], acc[2], acc[3]};
  float4 o1 = {acc[4], acc[5], acc[6], acc[7]};
  o[0] = o0; o[1] = o1;
}

extern "C" void kernel_launch(void* const* d_in, const int* in_sizes, int n_in,
                              void* d_out, int out_size, void* d_ws, size_t ws_size,
                              hipStream_t stream) {
  const float* x = (const float*)d_in[0];
  const float* rw = (const float*)d_in[1];
  const float* gup = (const float*)d_in[2];
  const float* dwn = (const float*)d_in[3];
  float* out = (float*)d_out;
  int T = in_sizes[0] / HID;

  char* ws = (char*)d_ws;
  size_t off = 0;
  auto alloc = [&](size_t b) { size_t o = off; off += (b + 255) & ~(size_t)255; return o; };
  unsigned short* xb = (unsigned short*)(ws + alloc((size_t)T * HID * 2));
  unsigned short* hbuf = (unsigned short*)(ws + alloc((size_t)CAP * INTER * 2));
  double* logits = (double*)(ws + alloc((size_t)T * NEXP * 8));
  float* topk_w = (float*)(ws + alloc((size_t)T * TOPK * 4));
  int* topk_i = (int*)(ws + alloc((size_t)T * TOPK * 4));
  int* counts = (int*)(ws + alloc(NEXP * 4));
  int* cursor = (int*)(ws + alloc(NEXP * 4));
  int* n_tiles_p = (int*)(ws + alloc(256));
  int* tile_expert = (int*)(ws + alloc(MAX_TILES * 4));
  int* slot_token = (int*)(ws + alloc(CAP * 4));
  float* slot_w = (float*)(ws + alloc(CAP * 4));
  int* slot_of = (int*)(ws + alloc((size_t)T * TOPK * 4));
  size_t needB = off;
  unsigned short* ybuf = (unsigned short*)(ws + alloc((size_t)CAP * HID * 2));
  size_t needA = off;

  int tier = (ws_size >= needA) ? 0 : 1;   // ws measured ~4 GiB -> tier A

  init_kernel<<<2048, 256, 0, stream>>>(out, slot_token, counts, T * HID, tier != 0);
  cvt_kernel<<<2048, 256, 0, stream>>>(x, xb, T * HID / 4);
  router_kernel<<<T / 64, 256, 0, stream>>>(x, rw, logits);
  topk_kernel<<<T / 4, 256, 0, stream>>>(logits, topk_w, topk_i, counts, T);
  scan_kernel<<<1, 64, 0, stream>>>(counts, cursor, tile_expert, n_tiles_p);
  scatter_kernel<<<(T + 255) / 256, 256, 0, stream>>>(topk_i, topk_w, cursor, slot_token,
                                                      slot_w, slot_of, T);
  gateup_v3<<<dim3(INTER / 128, MAX_TILES), 256, 0, stream>>>(
      xb, gup, slot_token, tile_expert, n_tiles_p, hbuf);
  if (tier == 0) {
    down_v3<true><<<dim3(HID / 128, MAX_TILES), 256, 0, stream>>>(
        hbuf, dwn, slot_token, slot_w, tile_expert, n_tiles_p, ybuf, out);
    gather_kernel<<<T, 256, 0, stream>>>(ybuf, slot_of, topk_w, out);
  } else {
    down_v3<false><<<dim3(HID / 128, MAX_TILES), 256, 0, stream>>>(
        hbuf, dwn, slot_token, slot_w, tile_expert, n_tiles_p, nullptr, out);
  }
}

// Round 4
// 1957.518 us; speedup vs baseline: 1.6345x; 1.6345x over previous
//
#include <hip/hip_runtime.h>
#include <math.h>

// OlmoeSparseMoeBlock: T=8192, H=2048, E=64, I=1024, top-8.
// v4: in-kernel fp32->bf16 weight conversion with COALESCED staging
//     (16 lanes x 16B contiguous per row, v1 layout) via v_cvt_pk_bf16_f32
//     + ds_write_b64 into XOR-swizzled LDS. Activations (xb, hbuf) bf16 via
//     global_load_lds(16B) pre-swizzled-source. No weight cvt passes.
// Tier A: down writes per-slot y (bf16), gather combines (no atomics).

#define NEXP 64
#define HID 2048
#define INTER 1024
#define TOPK 8
#define PM 128
#define MAX_TILES 576
#define CAP (MAX_TILES * PM)
#define BK 64

typedef __attribute__((ext_vector_type(8))) short bf16x8;
typedef __attribute__((ext_vector_type(4))) float f32x4;

__device__ __forceinline__ unsigned short f2bf(float f) {
  unsigned int u = __float_as_uint(f);
  u += 0x7fffu + ((u >> 16) & 1u);   // RNE
  return (unsigned short)(u >> 16);
}
__device__ __forceinline__ float bf2f(unsigned short u) {
  return __uint_as_float(((unsigned int)u) << 16);
}

// element-index XOR swizzle for [row][BK] bf16 tiles (16B-granular)
__device__ __forceinline__ int SW(int row, int k) {
  return (row * BK + k) ^ ((row & 7) << 3);
}

__device__ __forceinline__ void gload16(const unsigned short* g, unsigned short* l) {
  __builtin_amdgcn_global_load_lds((const __attribute__((address_space(1))) unsigned int*)g,
                                   (__attribute__((address_space(3))) unsigned int*)l, 16, 0, 0);
}

// load 4 fp32 (16B, coalesced across 16 lanes), cvt_pk -> 4 bf16, 8B swizzled write
__device__ __forceinline__ void stageBrow(const float* __restrict__ src, int row, int bc,
                                          unsigned short* lds) {
  float4 v = *(const float4*)src;
  unsigned int w0, w1;
  asm("v_cvt_pk_bf16_f32 %0, %1, %2" : "=v"(w0) : "v"(v.x), "v"(v.y));
  asm("v_cvt_pk_bf16_f32 %0, %1, %2" : "=v"(w1) : "v"(v.z), "v"(v.w));
  uint2 w = {w0, w1};
  *(uint2*)&lds[SW(row, bc)] = w;   // bc%8 in {0,4}: stays inside 16B granule
}

// ---------------- init ----------------
__global__ void init_kernel(float* out, int* slot_token, int* counts, int total, int zero_out) {
  int stride = gridDim.x * blockDim.x;
  for (int i = blockIdx.x * blockDim.x + threadIdx.x; i < total; i += stride) {
    if (zero_out) out[i] = 0.f;
    if (i < CAP) slot_token[i] = -1;
    if (i < NEXP) counts[i] = 0;
  }
}

// ---------------- x fp32 -> bf16 ----------------
__global__ void cvt_kernel(const float* __restrict__ src, unsigned short* __restrict__ dst, int n4) {
  int stride = gridDim.x * blockDim.x;
  for (int i = blockIdx.x * blockDim.x + threadIdx.x; i < n4; i += stride) {
    float4 v = ((const float4*)src)[i];
    ushort4 b;
    b.x = f2bf(v.x); b.y = f2bf(v.y); b.z = f2bf(v.z); b.w = f2bf(v.w);
    ((ushort4*)dst)[i] = b;
  }
}

// ---------------- router: fp64 logits [T][64] ----------------
__global__ void router_kernel(const float* __restrict__ x, const float* __restrict__ rw,
                              double* __restrict__ logits) {
  int t0 = blockIdx.x * 64;
  __shared__ float xs[64][33];
  __shared__ float wsm[64][33];
  int tid = threadIdx.x;
  int ti = tid >> 4, ei = tid & 15;
  double acc[4][4];
  for (int i = 0; i < 4; i++)
    for (int j = 0; j < 4; j++) acc[i][j] = 0.0;
  int srow = tid >> 3, sc = (tid & 7) * 4;
  for (int kb = 0; kb < HID; kb += 32) {
    for (int p = 0; p < 2; p++) {
      int r2 = srow + p * 32;
      float4 xv = *(const float4*)&x[(size_t)(t0 + r2) * HID + kb + sc];
      xs[r2][sc] = xv.x; xs[r2][sc + 1] = xv.y; xs[r2][sc + 2] = xv.z; xs[r2][sc + 3] = xv.w;
      float4 wv = *(const float4*)&rw[(size_t)r2 * HID + kb + sc];
      wsm[r2][sc] = wv.x; wsm[r2][sc + 1] = wv.y; wsm[r2][sc + 2] = wv.z; wsm[r2][sc + 3] = wv.w;
    }
    __syncthreads();
    for (int kk = 0; kk < 32; kk++) {
      float xa[4], wb[4];
      for (int i = 0; i < 4; i++) xa[i] = xs[ti * 4 + i][kk];
      for (int j = 0; j < 4; j++) wb[j] = wsm[ei * 4 + j][kk];
      for (int i = 0; i < 4; i++)
        for (int j = 0; j < 4; j++) acc[i][j] += (double)xa[i] * (double)wb[j];
    }
    __syncthreads();
  }
  for (int i = 0; i < 4; i++)
    for (int j = 0; j < 4; j++)
      logits[(size_t)(t0 + ti * 4 + i) * NEXP + ei * 4 + j] = acc[i][j];
}

// ---------------- softmax + top8 + counts ----------------
__global__ void topk_kernel(const double* __restrict__ logits, float* __restrict__ topk_w,
                            int* __restrict__ topk_i, int* __restrict__ counts, int T) {
  int t = blockIdx.x * 4 + (threadIdx.x >> 6);
  int lane = threadIdx.x & 63;
  if (t >= T) return;
  double v = logits[(size_t)t * NEXP + lane];
  double m = v;
  for (int off = 32; off; off >>= 1) {
    double o = __shfl_xor(m, off);
    if (o > m) m = o;
  }
  double ex = exp(v - m);
  double s = ex;
  for (int off = 32; off; off >>= 1) s += __shfl_xor(s, off);
  double cur = ex / s;
  for (int k = 0; k < TOPK; k++) {
    double bv = cur; int bi = lane;
    for (int off = 32; off; off >>= 1) {
      double ov = __shfl_xor(bv, off);
      int oi = __shfl_xor(bi, off);
      if (ov > bv || (ov == bv && oi < bi)) { bv = ov; bi = oi; }
    }
    if (lane == k) {
      topk_w[t * TOPK + k] = (float)bv;
      topk_i[t * TOPK + k] = bi;
      atomicAdd(&counts[bi], 1);
    }
    if (lane == bi) cur = -1.0;
  }
}

// ---------------- scan ----------------
__global__ void scan_kernel(const int* __restrict__ counts, int* cursor,
                            int* tile_expert, int* n_tiles_p) {
  if (threadIdx.x == 0 && blockIdx.x == 0) {
    int nt = 0;
    for (int e = 0; e < NEXP; e++) {
      cursor[e] = nt * PM;
      int c = counts[e];
      int k = (c + PM - 1) / PM;
      for (int i = 0; i < k; i++) tile_expert[nt++] = e;
    }
    *n_tiles_p = nt;
  }
}

// ---------------- scatter ----------------
__global__ void scatter_kernel(const int* __restrict__ topk_i, const float* __restrict__ topk_w,
                               int* cursor, int* slot_token, float* slot_w,
                               int* slot_of, int T) {
  int t = blockIdx.x * blockDim.x + threadIdx.x;
  if (t >= T) return;
  for (int k = 0; k < TOPK; k++) {
    int e = topk_i[t * TOPK + k];
    int pos = atomicAdd(&cursor[e], 1);
    slot_token[pos] = t;
    slot_w[pos] = topk_w[t * TOPK + k];
    slot_of[t * TOPK + k] = pos;
  }
}

// =====================================================================
// gate_up GEMM: A = xb (bf16, gload_lds), B = gup fp32 (coalesced reg->cvt_pk->LDS)
// =====================================================================
__global__ __launch_bounds__(256, 2) void gateup_v4(
    const unsigned short* __restrict__ xb, const float* __restrict__ gup,
    const int* __restrict__ slot_token, const int* __restrict__ tile_expert,
    const int* __restrict__ n_tiles_p, unsigned short* __restrict__ hbuf) {
  int tile = blockIdx.y;
  if (tile >= *n_tiles_p) return;
  int e = tile_expert[tile];
  int slot0 = tile * PM;
  int n0 = blockIdx.x * 128;
  __shared__ __align__(16) unsigned short As[128 * BK];
  __shared__ __align__(16) unsigned short Bgs[128 * BK];
  __shared__ __align__(16) unsigned short Bus[128 * BK];
  int tid = threadIdx.x;
  int wid = tid >> 6, lane = tid & 63;
  int lrow = lane >> 3, pc = lane & 7;

  // A staging: per-lane pre-swizzled global src, linear LDS dest
  const unsigned short* aptr[4];
  unsigned short* lA[4];
#pragma unroll
  for (int i = 0; i < 4; i++) {
    int r = wid * 32 + i * 8 + lrow;
    int sc = pc ^ (r & 7);
    int tok = slot_token[slot0 + r]; if (tok < 0) tok = 0;
    aptr[i] = xb + (size_t)tok * HID + sc * 8;
    lA[i] = &As[(wid * 32 + i * 8) * BK];
  }
  // B staging: coalesced — 16 lanes cover 64 consecutive fp32 of one row
  int brow = tid >> 4, bc = (tid & 15) * 4;
  const float* gsrc = gup + ((size_t)e * (2 * INTER) + (n0 + brow)) * HID + bc;
  const float* usrc = gsrc + (size_t)INTER * HID;

  f32x4 zero = {0.f, 0.f, 0.f, 0.f};
  f32x4 accg[4][4], accu[4][4];
#pragma unroll
  for (int i = 0; i < 4; i++)
#pragma unroll
    for (int j = 0; j < 4; j++) { accg[i][j] = zero; accu[i][j] = zero; }

  int wm = wid >> 1, wn = wid & 1, lr = lane & 15, lk = lane >> 4;

  for (int kb = 0; kb < HID; kb += BK) {
#pragma unroll
    for (int i = 0; i < 4; i++) gload16(aptr[i] + kb, lA[i]);
#pragma unroll
    for (int p = 0; p < 8; p++)
      stageBrow(gsrc + (size_t)p * 16 * HID + kb, brow + p * 16, bc, Bgs);
#pragma unroll
    for (int p = 0; p < 8; p++)
      stageBrow(usrc + (size_t)p * 16 * HID + kb, brow + p * 16, bc, Bus);
    __syncthreads();
#pragma unroll
    for (int kk = 0; kk < BK; kk += 32) {
      bf16x8 a[4], bgf[4], buf[4];
#pragma unroll
      for (int mf = 0; mf < 4; mf++)
        a[mf] = *(const bf16x8*)&As[SW(wm * 64 + mf * 16 + lr, kk + lk * 8)];
#pragma unroll
      for (int nf = 0; nf < 4; nf++) {
        bgf[nf] = *(const bf16x8*)&Bgs[SW(wn * 64 + nf * 16 + lr, kk + lk * 8)];
        buf[nf] = *(const bf16x8*)&Bus[SW(wn * 64 + nf * 16 + lr, kk + lk * 8)];
      }
#pragma unroll
      for (int mf = 0; mf < 4; mf++)
#pragma unroll
        for (int nf = 0; nf < 4; nf++) {
          accg[mf][nf] = __builtin_amdgcn_mfma_f32_16x16x32_bf16(a[mf], bgf[nf], accg[mf][nf], 0, 0, 0);
          accu[mf][nf] = __builtin_amdgcn_mfma_f32_16x16x32_bf16(a[mf], buf[nf], accu[mf][nf], 0, 0, 0);
        }
    }
    __syncthreads();
  }
#pragma unroll
  for (int mf = 0; mf < 4; mf++)
#pragma unroll
    for (int nf = 0; nf < 4; nf++)
#pragma unroll
      for (int r = 0; r < 4; r++) {
        int row = wm * 64 + mf * 16 + lk * 4 + r;
        int col = n0 + wn * 64 + nf * 16 + lr;
        float g = accg[mf][nf][r];
        float u = accu[mf][nf][r];
        float hv = (g / (1.f + __expf(-g))) * u;
        hbuf[(size_t)(slot0 + row) * INTER + col] = f2bf(hv);
      }
}

// =====================================================================
// down GEMM: A = hbuf (bf16, gload_lds), B = dwn fp32 (coalesced reg->cvt_pk->LDS)
// =====================================================================
template <bool STORE_Y>
__global__ __launch_bounds__(256, 3) void down_v4(
    const unsigned short* __restrict__ hbuf, const float* __restrict__ dwn,
    const int* __restrict__ slot_token, const float* __restrict__ slot_w,
    const int* __restrict__ tile_expert, const int* __restrict__ n_tiles_p,
    unsigned short* __restrict__ ybuf, float* __restrict__ out) {
  int tile = blockIdx.y;
  if (tile >= *n_tiles_p) return;
  int e = tile_expert[tile];
  int slot0 = tile * PM;
  int n0 = blockIdx.x * 128;
  __shared__ __align__(16) unsigned short Hs[128 * BK];
  __shared__ __align__(16) unsigned short Bd[128 * BK];
  int tid = threadIdx.x;
  int wid = tid >> 6, lane = tid & 63;
  int lrow = lane >> 3, pc = lane & 7;

  const unsigned short* hptr[4];
  unsigned short* lH[4];
#pragma unroll
  for (int i = 0; i < 4; i++) {
    int r = wid * 32 + i * 8 + lrow;
    int sc = pc ^ (r & 7);
    hptr[i] = hbuf + (size_t)(slot0 + r) * INTER + sc * 8;
    lH[i] = &Hs[(wid * 32 + i * 8) * BK];
  }
  int brow = tid >> 4, bc = (tid & 15) * 4;
  const float* dsrc = dwn + ((size_t)e * HID + (n0 + brow)) * INTER + bc;

  f32x4 zero = {0.f, 0.f, 0.f, 0.f};
  f32x4 acc[4][4];
#pragma unroll
  for (int i = 0; i < 4; i++)
#pragma unroll
    for (int j = 0; j < 4; j++) acc[i][j] = zero;

  int wm = wid >> 1, wn = wid & 1, lr = lane & 15, lk = lane >> 4;

  for (int kb = 0; kb < INTER; kb += BK) {
#pragma unroll
    for (int i = 0; i < 4; i++) gload16(hptr[i] + kb, lH[i]);
#pragma unroll
    for (int p = 0; p < 8; p++)
      stageBrow(dsrc + (size_t)p * 16 * INTER + kb, brow + p * 16, bc, Bd);
    __syncthreads();
#pragma unroll
    for (int kk = 0; kk < BK; kk += 32) {
      bf16x8 a[4], b[4];
#pragma unroll
      for (int mf = 0; mf < 4; mf++)
        a[mf] = *(const bf16x8*)&Hs[SW(wm * 64 + mf * 16 + lr, kk + lk * 8)];
#pragma unroll
      for (int nf = 0; nf < 4; nf++)
        b[nf] = *(const bf16x8*)&Bd[SW(wn * 64 + nf * 16 + lr, kk + lk * 8)];
#pragma unroll
      for (int mf = 0; mf < 4; mf++)
#pragma unroll
        for (int nf = 0; nf < 4; nf++)
          acc[mf][nf] = __builtin_amdgcn_mfma_f32_16x16x32_bf16(a[mf], b[nf], acc[mf][nf], 0, 0, 0);
    }
    __syncthreads();
  }
#pragma unroll
  for (int mf = 0; mf < 4; mf++)
#pragma unroll
    for (int r = 0; r < 4; r++) {
      int row = wm * 64 + mf * 16 + lk * 4 + r;
      int slot = slot0 + row;
      if (STORE_Y) {
#pragma unroll
        for (int nf = 0; nf < 4; nf++) {
          int col = n0 + wn * 64 + nf * 16 + lr;
          ybuf[(size_t)slot * HID + col] = f2bf(acc[mf][nf][r]);
        }
      } else {
        int t = slot_token[slot];
        if (t < 0) continue;
        float w = slot_w[slot];
#pragma unroll
        for (int nf = 0; nf < 4; nf++) {
          int col = n0 + wn * 64 + nf * 16 + lr;
          atomicAdd(&out[(size_t)t * HID + col], w * acc[mf][nf][r]);
        }
      }
    }
}

// ---------------- gather: out[t] = sum_k w_k * y[slot(t,k)] ----------------
__global__ void gather_kernel(const unsigned short* __restrict__ ybuf,
                              const int* __restrict__ slot_of,
                              const float* __restrict__ topk_w,
                              float* __restrict__ out) {
  int t = blockIdx.x;
  int c0 = threadIdx.x * 8;
  int slots[TOPK]; float w[TOPK];
#pragma unroll
  for (int k = 0; k < TOPK; k++) {
    slots[k] = slot_of[t * TOPK + k];
    w[k] = topk_w[t * TOPK + k];
  }
  float acc[8];
#pragma unroll
  for (int j = 0; j < 8; j++) acc[j] = 0.f;
#pragma unroll
  for (int k = 0; k < TOPK; k++) {
    const ushort4* p = (const ushort4*)(ybuf + (size_t)slots[k] * HID + c0);
    ushort4 v0 = p[0], v1 = p[1];
    acc[0] += w[k] * bf2f(v0.x); acc[1] += w[k] * bf2f(v0.y);
    acc[2] += w[k] * bf2f(v0.z); acc[3] += w[k] * bf2f(v0.w);
    acc[4] += w[k] * bf2f(v1.x); acc[5] += w[k] * bf2f(v1.y);
    acc[6] += w[k] * bf2f(v1.z); acc[7] += w[k] * bf2f(v1.w);
  }
  float4* o = (float4*)(out + (size_t)t * HID + c0);
  float4 o0 = {acc[0], acc[1], acc[2], acc[3]};
  float4 o1 = {acc[4], acc[5], acc[6], acc[7]};
  o[0] = o0; o[1] = o1;
}

extern "C" void kernel_launch(void* const* d_in, const int* in_sizes, int n_in,
                              void* d_out, int out_size, void* d_ws, size_t ws_size,
                              hipStream_t stream) {
  const float* x = (const float*)d_in[0];
  const float* rw = (const float*)d_in[1];
  const float* gup = (const float*)d_in[2];
  const float* dwn = (const float*)d_in[3];
  float* out = (float*)d_out;
  int T = in_sizes[0] / HID;

  char* ws = (char*)d_ws;
  size_t off = 0;
  auto alloc = [&](size_t b) { size_t o = off; off += (b + 255) & ~(size_t)255; return o; };
  unsigned short* xb = (unsigned short*)(ws + alloc((size_t)T * HID * 2));
  unsigned short* hbuf = (unsigned short*)(ws + alloc((size_t)CAP * INTER * 2));
  double* logits = (double*)(ws + alloc((size_t)T * NEXP * 8));
  float* topk_w = (float*)(ws + alloc((size_t)T * TOPK * 4));
  int* topk_i = (int*)(ws + alloc((size_t)T * TOPK * 4));
  int* counts = (int*)(ws + alloc(NEXP * 4));
  int* cursor = (int*)(ws + alloc(NEXP * 4));
  int* n_tiles_p = (int*)(ws + alloc(256));
  int* tile_expert = (int*)(ws + alloc(MAX_TILES * 4));
  int* slot_token = (int*)(ws + alloc(CAP * 4));
  float* slot_w = (float*)(ws + alloc(CAP * 4));
  int* slot_of = (int*)(ws + alloc((size_t)T * TOPK * 4));
  size_t needB = off;
  unsigned short* ybuf = (unsigned short*)(ws + alloc((size_t)CAP * HID * 2));
  size_t needA = off;

  int tier = (ws_size >= needA) ? 0 : 1;

  init_kernel<<<2048, 256, 0, stream>>>(out, slot_token, counts, T * HID, tier != 0);
  cvt_kernel<<<2048, 256, 0, stream>>>(x, xb, T * HID / 4);
  router_kernel<<<T / 64, 256, 0, stream>>>(x, rw, logits);
  topk_kernel<<<T / 4, 256, 0, stream>>>(logits, topk_w, topk_i, counts, T);
  scan_kernel<<<1, 64, 0, stream>>>(counts, cursor, tile_expert, n_tiles_p);
  scatter_kernel<<<(T + 255) / 256, 256, 0, stream>>>(topk_i, topk_w, cursor, slot_token,
                                                      slot_w, slot_of, T);
  gateup_v4<<<dim3(INTER / 128, MAX_TILES), 256, 0, stream>>>(
      xb, gup, slot_token, tile_expert, n_tiles_p, hbuf);
  if (tier == 0) {
    down_v4<true><<<dim3(HID / 128, MAX_TILES), 256, 0, stream>>>(
        hbuf, dwn, slot_token, slot_w, tile_expert, n_tiles_p, ybuf, out);
    gather_kernel<<<T, 256, 0, stream>>>(ybuf, slot_of, topk_w, out);
  } else {
    down_v4<false><<<dim3(HID / 128, MAX_TILES), 256, 0, stream>>>(
        hbuf, dwn, slot_token, slot_w, tile_expert, n_tiles_p, nullptr, out);
  }
}